// Round 7
// baseline (70.810 us; speedup 1.0000x reference)
//
#include <hip/hip_runtime.h>

#define DEV static __device__ __forceinline__

typedef unsigned short u16;
typedef unsigned int u32;
typedef float f32x4 __attribute__((ext_vector_type(4)));
typedef __bf16 bf16x8 __attribute__((ext_vector_type(8)));
typedef unsigned short u16x8 __attribute__((ext_vector_type(8)));
typedef unsigned int u32x2 __attribute__((ext_vector_type(2)));
typedef unsigned int u32x4 __attribute__((ext_vector_type(4)));

constexpr int H = 16, DIN = 1024, DH = 64, S = 2048, T = 2048;
constexpr float SM_C = 0.18033688011112042f;  // log2(e)/8 folded into Wq,bq

DEV u16 f2bf(float f) { return __builtin_bit_cast(u16, (__bf16)f); }
DEV float bf2f(u16 u) { u32 i = (u32)u << 16; return __builtin_bit_cast(float, i); }
DEV bf16x8 ld_bf8(const u16* p) { return __builtin_bit_cast(bf16x8, *(const u16x8*)p); }
DEV u32 cvtpk(float lo, float hi) {
  u32 r; asm("v_cvt_pk_bf16_f32 %0, %1, %2" : "=v"(r) : "v"(lo), "v"(hi)); return r;
}

// async global->LDS, 16B/lane; LDS dest must be wave-uniform base + lane*16
#define GLOAD16(gp, lp) __builtin_amdgcn_global_load_lds( \
    (const __attribute__((address_space(1))) void*)(gp),  \
    (__attribute__((address_space(3))) void*)(lp), 16, 0, 0)

// ---------------- prep: fp32->bf16 tokens + all weight transposes ----------------
__global__ __launch_bounds__(256) void prep_kernel(
    const float* __restrict__ cur, const float* __restrict__ ctx,
    const float* __restrict__ Wq, const float* __restrict__ Wk,
    const float* __restrict__ Wv, const float* __restrict__ Wo,
    u16* __restrict__ cur_bf, u16* __restrict__ ctx_bf,
    u16* __restrict__ WqT, u16* __restrict__ WkvT, u16* __restrict__ WoT) {
  __shared__ alignas(16) float tile[64 * 68];
  int bid = blockIdx.x, tid = threadIdx.x;
  if (bid < 2048) {  // cvt part
    int i = bid * 256 + tid;
    const float* in; u16* out; int j;
    if (i < 262144) { in = cur; out = cur_bf; j = i; }
    else            { in = ctx; out = ctx_bf; j = i - 262144; }
    const float4* p = (const float4*)(in + (size_t)j * 8);
    float4 x = p[0], y = p[1];
    u16x8 o;
    o[0] = f2bf(x.x); o[1] = f2bf(x.y); o[2] = f2bf(x.z); o[3] = f2bf(x.w);
    o[4] = f2bf(y.x); o[5] = f2bf(y.y); o[6] = f2bf(y.z); o[7] = f2bf(y.w);
    *(u16x8*)(out + (size_t)j * 8) = o;
    return;
  }
  int t = bid - 2048, k0 = (t & 15) * 64, y = t >> 4;  // y in 0..48
  const float* W; u16* Wt; float scale = 1.0f;
  if (y < 16)      { W = Wq + (size_t)y * DIN * DH;        Wt = WqT + (size_t)y * DH * DIN; scale = SM_C; }
  else if (y < 32) { W = Wk + (size_t)(y - 16) * DIN * DH; Wt = WkvT + (size_t)(y - 16) * DH * DIN; }
  else if (y < 48) { W = Wv + (size_t)(y - 32) * DIN * DH; Wt = WkvT + (size_t)(y - 16) * DH * DIN; }
  else             { W = Wo;                               Wt = WoT; }
#pragma unroll
  for (int it = 0; it < 4; ++it) {
    int slot = it * 256 + tid;
    int i = slot >> 4, j4 = (slot & 15) * 4;
    *(float4*)&tile[i * 68 + j4] = *(const float4*)&W[(size_t)(k0 + i) * 64 + j4];
  }
  __syncthreads();
  int n = tid >> 2, kb = (tid & 3) * 16;
  u16x8 o0, o1;
#pragma unroll
  for (int j = 0; j < 8; ++j) o0[j] = f2bf(tile[(kb + j) * 68 + n] * scale);
#pragma unroll
  for (int j = 0; j < 8; ++j) o1[j] = f2bf(tile[(kb + 8 + j) * 68 + n] * scale);
  *(u16x8*)&Wt[(size_t)n * DIN + k0 + kb] = o0;
  *(u16x8*)&Wt[(size_t)n * DIN + k0 + kb + 8] = o1;
}

// ---------------- fused QKV GEMM: 128x64 tiles (768 blocks = 3/CU), dbuf, V^T direct ----------------
__global__ __launch_bounds__(256) void gemm_qkv_kernel(
    const u16* __restrict__ Acur, const u16* __restrict__ Actx,
    const u16* __restrict__ WqT, const u16* __restrict__ WkvT,
    const float* __restrict__ bq, const float* __restrict__ bk, const float* __restrict__ bv,
    u16* __restrict__ Qall, u16* __restrict__ Kall, u16* __restrict__ VtAll) {
  __shared__ alignas(16) u16 As[2][128 * 64];
  __shared__ alignas(16) u16 Bs[2][64 * 64];
  int bid = blockIdx.x;
  const u16 *A, *W; int m0, n0, mode;  // mode 0=Q,1=K,2=V^T
  if (bid < 256)      { A = Acur; W = WqT;               m0 = (bid >> 4) * 128;  n0 = (bid & 15) * 64; mode = 0; }
  else if (bid < 512) { int b = bid - 256; A = Actx; W = WkvT;               m0 = (b >> 4) * 128; n0 = (b & 15) * 64; mode = 1; }
  else                { int b = bid - 512; A = Actx; W = WkvT + 1024 * 1024; m0 = (b >> 4) * 128; n0 = (b & 15) * 64; mode = 2; }
  int tid = threadIdx.x, w = tid >> 6, l = tid & 63, g = l >> 4, r = l & 15;
  auto stage = [&](int buf, int kt) {
#pragma unroll
    for (int it = 0; it < 4; ++it) {
      int c = it * 256 + tid, row = c >> 3, q = c & 7;
      GLOAD16(&A[(size_t)(m0 + row) * DIN + kt + ((q ^ (row & 7)) << 3)], &As[buf][c * 8]);
    }
#pragma unroll
    for (int it = 0; it < 2; ++it) {
      int c = it * 256 + tid, row = c >> 3, q = c & 7;
      GLOAD16(&W[(size_t)(n0 + row) * DIN + kt + ((q ^ (row & 7)) << 3)], &Bs[buf][c * 8]);
    }
  };
  stage(0, 0);
  __syncthreads();
  f32x4 acc[2][4] = {};
  for (int t = 0; t < 16; ++t) {
    if (t < 15) stage((t + 1) & 1, (t + 1) * 64);  // prefetch in flight across compute
    int cur = t & 1;
#pragma unroll
    for (int kk = 0; kk < 2; ++kk) {
      int qo = (((kk << 2) | g) ^ (r & 7)) << 3;
      bf16x8 a0 = ld_bf8(&As[cur][(w * 32 + r) * 64 + qo]);
      bf16x8 a1 = ld_bf8(&As[cur][(w * 32 + 16 + r) * 64 + qo]);
      if (mode < 2) {
#pragma unroll
        for (int nf = 0; nf < 4; ++nf) {
          bf16x8 b = ld_bf8(&Bs[cur][(nf * 16 + r) * 64 + qo]);
          acc[0][nf] = __builtin_amdgcn_mfma_f32_16x16x32_bf16(a0, b, acc[0][nf], 0, 0, 0);
          acc[1][nf] = __builtin_amdgcn_mfma_f32_16x16x32_bf16(a1, b, acc[1][nf], 0, 0, 0);
        }
      } else {  // transposed output: D rows = weight-d, cols = tokens
#pragma unroll
        for (int nf = 0; nf < 4; ++nf) {
          bf16x8 b = ld_bf8(&Bs[cur][(nf * 16 + r) * 64 + qo]);
          acc[0][nf] = __builtin_amdgcn_mfma_f32_16x16x32_bf16(b, a0, acc[0][nf], 0, 0, 0);
          acc[1][nf] = __builtin_amdgcn_mfma_f32_16x16x32_bf16(b, a1, acc[1][nf], 0, 0, 0);
        }
      }
    }
    __syncthreads();  // ONE barrier: drains prefetch + protects buffer swap
  }
  if (mode < 2) {
    u16* dst = (mode == 0) ? Qall : Kall;
    const float* bias = (mode == 0) ? bq : bk;
    float bscale = (mode == 0) ? SM_C : 1.0f;
#pragma unroll
    for (int mi = 0; mi < 2; ++mi)
#pragma unroll
      for (int nf = 0; nf < 4; ++nf)
#pragma unroll
        for (int rr = 0; rr < 4; ++rr) {
          int row = m0 + w * 32 + mi * 16 + 4 * g + rr, col = n0 + nf * 16 + r;
          dst[(size_t)row * 1024 + col] = f2bf(acc[mi][nf][rr] + bias[col] * bscale);
        }
  } else {
#pragma unroll
    for (int mi = 0; mi < 2; ++mi)
#pragma unroll
      for (int nf = 0; nf < 4; ++nf)
#pragma unroll
        for (int rr = 0; rr < 4; ++rr) {
          int d = n0 + nf * 16 + 4 * g + rr, tok = m0 + w * 32 + mi * 16 + r;
          VtAll[(size_t)d * 2048 + tok] = f2bf(acc[mi][nf][rr] + bv[d]);
        }
  }
}

// ---------------- flash attention: 64q/wave, 4-buffer staging (barrier per 2 tiles), setprio ----------------
__global__ __launch_bounds__(256, 2) void attn_kernel(
    const u16* __restrict__ Qall, const u16* __restrict__ Kall,
    const u16* __restrict__ VtAll, u16* __restrict__ OP, float* __restrict__ LP) {
  int qb = blockIdx.x, h = blockIdx.y, ts = blockIdx.z;
  int tid = threadIdx.x, w = tid >> 6, l = tid & 63, g = l >> 4, r = l & 15;
  __shared__ alignas(16) u16 Ks[4][64 * 64];
  __shared__ alignas(16) u16 Vs[4][64 * 64];
  const int q0 = qb * 256 + w * 64;
  bf16x8 qf[4][2];
#pragma unroll
  for (int sub = 0; sub < 4; ++sub)
#pragma unroll
    for (int kk = 0; kk < 2; ++kk)
      qf[sub][kk] = ld_bf8(&Qall[(size_t)(q0 + sub * 16 + r) * 1024 + h * 64 + kk * 32 + 8 * g]);
  f32x4 o[4][4] = {};
  float lsum[4] = {0.f, 0.f, 0.f, 0.f};
  const int tBeg = ts * 512;

  auto stage = [&](int buf, int t0) {
#pragma unroll
    for (int it = 0; it < 2; ++it) {
      int c = it * 256 + tid, row = c >> 3, q = c & 7;
      int qs = (q ^ (row & 7)) << 3;
      GLOAD16(&Kall[(size_t)(t0 + row) * 1024 + h * 64 + qs], &Ks[buf][c * 8]);
      GLOAD16(&VtAll[(size_t)(h * 64 + row) * 2048 + t0 + qs], &Vs[buf][c * 8]);
    }
  };
  auto compute = [&](int buf) {
    // S^T = K Q : sacc[sub][nf][rr] = S[t=nf*16+4g+rr][q=r]  (Q pre-scaled by log2e/8)
    f32x4 sacc[4][4] = {};
    __builtin_amdgcn_s_setprio(1);
#pragma unroll
    for (int kk = 0; kk < 2; ++kk) {
      int qo = (((kk << 2) | g) ^ (r & 7)) << 3;
#pragma unroll
      for (int nf = 0; nf < 4; ++nf) {
        bf16x8 kf = ld_bf8(&Ks[buf][(nf * 16 + r) * 64 + qo]);
#pragma unroll
        for (int sub = 0; sub < 4; ++sub)
          sacc[sub][nf] = __builtin_amdgcn_mfma_f32_16x16x32_bf16(kf, qf[sub][kk], sacc[sub][nf], 0, 0, 0);
      }
    }
    __builtin_amdgcn_s_setprio(0);
    // P = 2^sacc, pack to bf16 dwords c[sub][nf][s2] = {t=16nf+4g+2s2, +1}
    u32 c[4][4][2];
#pragma unroll
    for (int sub = 0; sub < 4; ++sub)
#pragma unroll
      for (int nf = 0; nf < 4; ++nf) {
        float p0 = __builtin_amdgcn_exp2f(sacc[sub][nf][0]);
        float p1 = __builtin_amdgcn_exp2f(sacc[sub][nf][1]);
        float p2 = __builtin_amdgcn_exp2f(sacc[sub][nf][2]);
        float p3 = __builtin_amdgcn_exp2f(sacc[sub][nf][3]);
        lsum[sub] += (p0 + p1) + (p2 + p3);
        c[sub][nf][0] = cvtpk(p0, p1);
        c[sub][nf][1] = cvtpk(p2, p3);
      }
    // O^T += V^T P^T : B-frag built in-register via permlane32+16 swap
    __builtin_amdgcn_s_setprio(1);
#pragma unroll
    for (int kk = 0; kk < 2; ++kk) {
      int qo = (((kk << 2) | g) ^ (r & 7)) << 3;
      bf16x8 vf[4];
#pragma unroll
      for (int nf = 0; nf < 4; ++nf) vf[nf] = ld_bf8(&Vs[buf][(nf * 16 + r) * 64 + qo]);
#pragma unroll
      for (int sub = 0; sub < 4; ++sub) {
        u32 dw[4];
#pragma unroll
        for (int s2 = 0; s2 < 2; ++s2) {
          u32x2 t1 = __builtin_amdgcn_permlane32_swap(c[sub][2 * kk][s2], c[sub][2 * kk + 1][s2],
                                                      false, false);
          u32x2 t2 = __builtin_amdgcn_permlane16_swap(t1.x, t1.y, false, false);
          dw[s2] = t2.x; dw[2 + s2] = t2.y;
        }
        bf16x8 pB = __builtin_bit_cast(bf16x8, (u32x4){dw[0], dw[1], dw[2], dw[3]});
#pragma unroll
        for (int nf = 0; nf < 4; ++nf)
          o[sub][nf] = __builtin_amdgcn_mfma_f32_16x16x32_bf16(vf[nf], pB, o[sub][nf], 0, 0, 0);
      }
    }
    __builtin_amdgcn_s_setprio(0);
  };

  stage(0, tBeg);
  stage(1, tBeg + 64);
  __syncthreads();
  for (int tt = 0; tt < 8; tt += 2) {
    if (tt + 2 < 8) {  // prefetch 2 tiles ahead; they have 2 compute phases to land
      stage((tt + 2) & 3, tBeg + (tt + 2) * 64);
      stage((tt + 3) & 3, tBeg + (tt + 3) * 64);
    }
    compute(tt & 3);
    compute((tt + 1) & 3);
    __syncthreads();  // one barrier per 2 tiles: drains prefetch + protects buf reuse
  }
  // epilogue: O^T layout — lane holds d = nf*16+4g+rr (consecutive rr), q = r
#pragma unroll
  for (int sub = 0; sub < 4; ++sub) {
    float ls = lsum[sub];
    ls += __shfl_xor(ls, 16, 64);
    ls += __shfl_xor(ls, 32, 64);
    int s = q0 + sub * 16 + r;
    if (l < 16) LP[(size_t)(ts * 16 + h) * 2048 + s] = ls;
#pragma unroll
    for (int nf = 0; nf < 4; ++nf) {
      uint2 pd;
      pd.x = cvtpk(o[sub][nf][0], o[sub][nf][1]);
      pd.y = cvtpk(o[sub][nf][2], o[sub][nf][3]);
      *(uint2*)&OP[((size_t)(ts * 16 + h) * 2048 + s) * 64 + nf * 16 + 4 * g] = pd;
    }
  }
}

// ---------------- out-proj partial GEMM with FUSED combine (no G buffer) ----------------
// block (bx, kz): A-tile = G[bx*128 .. +127][kz*64 .. +63] computed on the fly from OP/LP.
// G row m = bx*128+row -> h = bx, s = row*16 + kz, col c = kz*64 + d (d = 0..63).
__global__ __launch_bounds__(256) void oproj_part_kernel(const u16* __restrict__ OP,
                                                         const float* __restrict__ LP,
                                                         const u16* __restrict__ WoT,
                                                         float* __restrict__ Part) {
  __shared__ alignas(16) u16 As[128 * 64];
  __shared__ alignas(16) u16 Bs[64 * 64];
  int bx = blockIdx.x, kz = blockIdx.y, kt = kz * 64;
  int tid = threadIdx.x, w = tid >> 6, l = tid & 63, g = l >> 4, r = l & 15;
  // B stage (async) first so it overlaps the fused-combine math
#pragma unroll
  for (int it = 0; it < 2; ++it) {
    int c = it * 256 + tid, row = c >> 3, q = c & 7;
    GLOAD16(&WoT[(size_t)row * DIN + kt + ((q ^ (row & 7)) << 3)], &Bs[c * 8]);
  }
  // A stage: combine 4 T-split partials, normalize, write swizzled LDS
#pragma unroll
  for (int it = 0; it < 4; ++it) {
    int c = it * 256 + tid, row = c >> 3, q = c & 7, qs = q ^ (row & 7);
    int s = row * 16 + kz;
    float a8[8] = {};
    float lsum = 0.f;
#pragma unroll
    for (int ts = 0; ts < 4; ++ts) {
      u16x8 v = *(const u16x8*)&OP[((size_t)(ts * 16 + bx) * 2048 + s) * 64 + qs * 8];
#pragma unroll
      for (int e = 0; e < 8; ++e) a8[e] += bf2f(v[e]);
      lsum += LP[(size_t)(ts * 16 + bx) * 2048 + s];
    }
    float inv = 1.0f / lsum;
    u16x8 ov;
#pragma unroll
    for (int e = 0; e < 8; ++e) ov[e] = f2bf(a8[e] * inv);
    *(u16x8*)&As[c * 8] = ov;
  }
  __syncthreads();
  f32x4 acc[2][4] = {};
#pragma unroll
  for (int kk = 0; kk < 2; ++kk) {
    int qo = (((kk << 2) | g) ^ (r & 7)) << 3;
    bf16x8 a0 = ld_bf8(&As[(w * 32 + r) * 64 + qo]);
    bf16x8 a1 = ld_bf8(&As[(w * 32 + 16 + r) * 64 + qo]);
#pragma unroll
    for (int nf = 0; nf < 4; ++nf) {
      bf16x8 b = ld_bf8(&Bs[(nf * 16 + r) * 64 + qo]);
      acc[0][nf] = __builtin_amdgcn_mfma_f32_16x16x32_bf16(a0, b, acc[0][nf], 0, 0, 0);
      acc[1][nf] = __builtin_amdgcn_mfma_f32_16x16x32_bf16(a1, b, acc[1][nf], 0, 0, 0);
    }
  }
#pragma unroll
  for (int mi = 0; mi < 2; ++mi)
#pragma unroll
    for (int nf = 0; nf < 4; ++nf)
#pragma unroll
      for (int rr = 0; rr < 4; ++rr)
        Part[((size_t)kz * 2048 + bx * 128 + w * 32 + mi * 16 + 4 * g + rr) * 64 + nf * 16 + r] =
            acc[mi][nf][rr];
}

__global__ __launch_bounds__(256) void oproj_reduce_kernel(const float* __restrict__ Part,
                                                           const float* __restrict__ bo,
                                                           float* __restrict__ out) {
  int i4 = (blockIdx.x * 256 + threadIdx.x) * 4;  // 32768 threads x 4 f32
  int d = i4 & 63;
  float4 s = {bo[d], bo[d + 1], bo[d + 2], bo[d + 3]};
#pragma unroll
  for (int kz = 0; kz < 16; ++kz) {
    float4 p = *(const float4*)&Part[(size_t)kz * 131072 + i4];
    s.x += p.x; s.y += p.y; s.z += p.z; s.w += p.w;
  }
  *(float4*)&out[i4] = s;
}

extern "C" void kernel_launch(void* const* d_in, const int* in_sizes, int n_in,
                              void* d_out, int out_size, void* d_ws, size_t ws_size,
                              hipStream_t stream) {
  const float* cur = (const float*)d_in[0];
  const float* ctx = (const float*)d_in[1];
  const float* Wq = (const float*)d_in[2];
  const float* bq = (const float*)d_in[3];
  const float* Wk = (const float*)d_in[4];
  const float* bk = (const float*)d_in[5];
  const float* Wv = (const float*)d_in[6];
  const float* bv = (const float*)d_in[7];
  const float* Wo = (const float*)d_in[8];
  const float* bo = (const float*)d_in[9];
  float* out = (float*)d_out;

  char* ws = (char*)d_ws;
  const size_t MB = 1ull << 20;
  u16* cur_bf = (u16*)(ws + 0 * MB);
  u16* ctx_bf = (u16*)(ws + 4 * MB);
  u16* WqT    = (u16*)(ws + 8 * MB);
  u16* WkvT   = (u16*)(ws + 10 * MB);
  u16* WoT    = (u16*)(ws + 14 * MB);
  u16* Qall   = (u16*)(ws + 15 * MB);
  u16* Kall   = (u16*)(ws + 19 * MB);
  u16* VtAll  = (u16*)(ws + 23 * MB);
  u16* OP     = (u16*)(ws + 27 * MB);   // [4][16][2048][64] bf16 = 16MB
  float* LP   = (float*)(ws + 43 * MB); // [4][16][2048] f32 = 512KB
  float* Part = (float*)(ws + 44 * MB); // [16][2048][64] f32 = 8MB

  prep_kernel<<<2832, 256, 0, stream>>>(cur, ctx, Wq, Wk, Wv, Wo, cur_bf, ctx_bf,
                                        WqT, WkvT, WoT);
  gemm_qkv_kernel<<<768, 256, 0, stream>>>(cur_bf, ctx_bf, WqT, WkvT, bq, bk, bv,
                                           Qall, Kall, VtAll);
  attn_kernel<<<dim3(8, 16, 4), 256, 0, stream>>>(Qall, Kall, VtAll, OP, LP);
  oproj_part_kernel<<<dim3(16, 16), 256, 0, stream>>>(OP, LP, WoT, Part);
  oproj_reduce_kernel<<<128, 256, 0, stream>>>(Part, bo, out);
}

// Round 8
// 67.564 us; speedup vs baseline: 1.0480x; 1.0480x over previous
//
#include <hip/hip_runtime.h>

#define DEV static __device__ __forceinline__

typedef unsigned short u16;
typedef unsigned int u32;
typedef float f32x4 __attribute__((ext_vector_type(4)));
typedef __bf16 bf16x8 __attribute__((ext_vector_type(8)));
typedef unsigned short u16x8 __attribute__((ext_vector_type(8)));
typedef unsigned int u32x2 __attribute__((ext_vector_type(2)));
typedef unsigned int u32x4 __attribute__((ext_vector_type(4)));

constexpr int H = 16, DIN = 1024, DH = 64, S = 2048, T = 2048;
constexpr float SM_C = 0.18033688011112042f;  // log2(e)/8 folded into Wq,bq

DEV u16 f2bf(float f) { return __builtin_bit_cast(u16, (__bf16)f); }
DEV float bf2f(u16 u) { u32 i = (u32)u << 16; return __builtin_bit_cast(float, i); }
DEV bf16x8 ld_bf8(const u16* p) { return __builtin_bit_cast(bf16x8, *(const u16x8*)p); }
DEV u32 cvtpk(float lo, float hi) {
  u32 r; asm("v_cvt_pk_bf16_f32 %0, %1, %2" : "=v"(r) : "v"(lo), "v"(hi)); return r;
}

// async global->LDS, 16B/lane; LDS dest must be wave-uniform base + lane*16
#define GLOAD16(gp, lp) __builtin_amdgcn_global_load_lds( \
    (const __attribute__((address_space(1))) void*)(gp),  \
    (__attribute__((address_space(3))) void*)(lp), 16, 0, 0)

// ---------------- prep: fp32->bf16 tokens + all weight transposes ----------------
__global__ __launch_bounds__(256) void prep_kernel(
    const float* __restrict__ cur, const float* __restrict__ ctx,
    const float* __restrict__ Wq, const float* __restrict__ Wk,
    const float* __restrict__ Wv, const float* __restrict__ Wo,
    u16* __restrict__ cur_bf, u16* __restrict__ ctx_bf,
    u16* __restrict__ WqT, u16* __restrict__ WkvT, u16* __restrict__ WoT) {
  __shared__ alignas(16) float tile[64 * 68];
  int bid = blockIdx.x, tid = threadIdx.x;
  if (bid < 2048) {  // cvt part
    int i = bid * 256 + tid;
    const float* in; u16* out; int j;
    if (i < 262144) { in = cur; out = cur_bf; j = i; }
    else            { in = ctx; out = ctx_bf; j = i - 262144; }
    const float4* p = (const float4*)(in + (size_t)j * 8);
    float4 x = p[0], y = p[1];
    u16x8 o;
    o[0] = f2bf(x.x); o[1] = f2bf(x.y); o[2] = f2bf(x.z); o[3] = f2bf(x.w);
    o[4] = f2bf(y.x); o[5] = f2bf(y.y); o[6] = f2bf(y.z); o[7] = f2bf(y.w);
    *(u16x8*)(out + (size_t)j * 8) = o;
    return;
  }
  int t = bid - 2048, k0 = (t & 15) * 64, y = t >> 4;  // y in 0..48
  const float* W; u16* Wt; float scale = 1.0f;
  if (y < 16)      { W = Wq + (size_t)y * DIN * DH;        Wt = WqT + (size_t)y * DH * DIN; scale = SM_C; }
  else if (y < 32) { W = Wk + (size_t)(y - 16) * DIN * DH; Wt = WkvT + (size_t)(y - 16) * DH * DIN; }
  else if (y < 48) { W = Wv + (size_t)(y - 32) * DIN * DH; Wt = WkvT + (size_t)(y - 16) * DH * DIN; }
  else             { W = Wo;                               Wt = WoT; }
#pragma unroll
  for (int it = 0; it < 4; ++it) {
    int slot = it * 256 + tid;
    int i = slot >> 4, j4 = (slot & 15) * 4;
    *(float4*)&tile[i * 68 + j4] = *(const float4*)&W[(size_t)(k0 + i) * 64 + j4];
  }
  __syncthreads();
  int n = tid >> 2, kb = (tid & 3) * 16;
  u16x8 o0, o1;
#pragma unroll
  for (int j = 0; j < 8; ++j) o0[j] = f2bf(tile[(kb + j) * 68 + n] * scale);
#pragma unroll
  for (int j = 0; j < 8; ++j) o1[j] = f2bf(tile[(kb + 8 + j) * 68 + n] * scale);
  *(u16x8*)&Wt[(size_t)n * DIN + k0 + kb] = o0;
  *(u16x8*)&Wt[(size_t)n * DIN + k0 + kb + 8] = o1;
}

// ---------------- fused QKV GEMM: 128x64 tiles, dbuf, V^T direct, XCD swizzle ----------------
__global__ __launch_bounds__(256) void gemm_qkv_kernel(
    const u16* __restrict__ Acur, const u16* __restrict__ Actx,
    const u16* __restrict__ WqT, const u16* __restrict__ WkvT,
    const float* __restrict__ bq, const float* __restrict__ bk, const float* __restrict__ bv,
    u16* __restrict__ Qall, u16* __restrict__ Kall, u16* __restrict__ VtAll) {
  __shared__ alignas(16) u16 As[2][128 * 64];
  __shared__ alignas(16) u16 Bs[2][64 * 64];
  // T1 XCD swizzle: 768 blocks = 8 XCDs x 96 contiguous logical blocks.
  // HW round-robins blockIdx.x%8 over XCDs -> each XCD gets a contiguous
  // logical chunk; neighboring tiles (shared A/W panels) become L2-local.
  int bid = (blockIdx.x & 7) * 96 + (blockIdx.x >> 3);
  const u16 *A, *W; int m0, n0, mode;  // mode 0=Q,1=K,2=V^T
  if (bid < 256)      { A = Acur; W = WqT;               m0 = (bid >> 4) * 128;  n0 = (bid & 15) * 64; mode = 0; }
  else if (bid < 512) { int b = bid - 256; A = Actx; W = WkvT;               m0 = (b >> 4) * 128; n0 = (b & 15) * 64; mode = 1; }
  else                { int b = bid - 512; A = Actx; W = WkvT + 1024 * 1024; m0 = (b >> 4) * 128; n0 = (b & 15) * 64; mode = 2; }
  int tid = threadIdx.x, w = tid >> 6, l = tid & 63, g = l >> 4, r = l & 15;
  auto stage = [&](int buf, int kt) {
#pragma unroll
    for (int it = 0; it < 4; ++it) {
      int c = it * 256 + tid, row = c >> 3, q = c & 7;
      GLOAD16(&A[(size_t)(m0 + row) * DIN + kt + ((q ^ (row & 7)) << 3)], &As[buf][c * 8]);
    }
#pragma unroll
    for (int it = 0; it < 2; ++it) {
      int c = it * 256 + tid, row = c >> 3, q = c & 7;
      GLOAD16(&W[(size_t)(n0 + row) * DIN + kt + ((q ^ (row & 7)) << 3)], &Bs[buf][c * 8]);
    }
  };
  stage(0, 0);
  __syncthreads();
  f32x4 acc[2][4] = {};
  for (int t = 0; t < 16; ++t) {
    if (t < 15) stage((t + 1) & 1, (t + 1) * 64);  // prefetch in flight across compute
    int cur = t & 1;
#pragma unroll
    for (int kk = 0; kk < 2; ++kk) {
      int qo = (((kk << 2) | g) ^ (r & 7)) << 3;
      bf16x8 a0 = ld_bf8(&As[cur][(w * 32 + r) * 64 + qo]);
      bf16x8 a1 = ld_bf8(&As[cur][(w * 32 + 16 + r) * 64 + qo]);
      if (mode < 2) {
#pragma unroll
        for (int nf = 0; nf < 4; ++nf) {
          bf16x8 b = ld_bf8(&Bs[cur][(nf * 16 + r) * 64 + qo]);
          acc[0][nf] = __builtin_amdgcn_mfma_f32_16x16x32_bf16(a0, b, acc[0][nf], 0, 0, 0);
          acc[1][nf] = __builtin_amdgcn_mfma_f32_16x16x32_bf16(a1, b, acc[1][nf], 0, 0, 0);
        }
      } else {  // transposed output: D rows = weight-d, cols = tokens
#pragma unroll
        for (int nf = 0; nf < 4; ++nf) {
          bf16x8 b = ld_bf8(&Bs[cur][(nf * 16 + r) * 64 + qo]);
          acc[0][nf] = __builtin_amdgcn_mfma_f32_16x16x32_bf16(b, a0, acc[0][nf], 0, 0, 0);
          acc[1][nf] = __builtin_amdgcn_mfma_f32_16x16x32_bf16(b, a1, acc[1][nf], 0, 0, 0);
        }
      }
    }
    __syncthreads();  // ONE barrier: drains prefetch + protects buffer swap
  }
  if (mode < 2) {
    u16* dst = (mode == 0) ? Qall : Kall;
    const float* bias = (mode == 0) ? bq : bk;
    float bscale = (mode == 0) ? SM_C : 1.0f;
#pragma unroll
    for (int mi = 0; mi < 2; ++mi)
#pragma unroll
      for (int nf = 0; nf < 4; ++nf)
#pragma unroll
        for (int rr = 0; rr < 4; ++rr) {
          int row = m0 + w * 32 + mi * 16 + 4 * g + rr, col = n0 + nf * 16 + r;
          dst[(size_t)row * 1024 + col] = f2bf(acc[mi][nf][rr] + bias[col] * bscale);
        }
  } else {
#pragma unroll
    for (int mi = 0; mi < 2; ++mi)
#pragma unroll
      for (int nf = 0; nf < 4; ++nf)
#pragma unroll
        for (int rr = 0; rr < 4; ++rr) {
          int d = n0 + nf * 16 + 4 * g + rr, tok = m0 + w * 32 + mi * 16 + r;
          VtAll[(size_t)d * 2048 + tok] = f2bf(acc[mi][nf][rr] + bv[d]);
        }
  }
}

// ---------------- flash attention: 64q/wave (4 subs), swapped QK^T, permlane P ----------------
__global__ __launch_bounds__(256, 2) void attn_kernel(
    const u16* __restrict__ Qall, const u16* __restrict__ Kall,
    const u16* __restrict__ VtAll, u16* __restrict__ OP, float* __restrict__ LP) {
  int qb = blockIdx.x, h = blockIdx.y, ts = blockIdx.z;
  int tid = threadIdx.x, w = tid >> 6, l = tid & 63, g = l >> 4, r = l & 15;
  __shared__ alignas(16) u16 Ks[2][64 * 64];
  __shared__ alignas(16) u16 Vs[2][64 * 64];
  const int q0 = qb * 256 + w * 64;
  bf16x8 qf[4][2];
#pragma unroll
  for (int sub = 0; sub < 4; ++sub)
#pragma unroll
    for (int kk = 0; kk < 2; ++kk)
      qf[sub][kk] = ld_bf8(&Qall[(size_t)(q0 + sub * 16 + r) * 1024 + h * 64 + kk * 32 + 8 * g]);
  f32x4 o[4][4] = {};
  float lsum[4] = {0.f, 0.f, 0.f, 0.f};
  const int tBeg = ts * 512, tEnd = tBeg + 512;

  auto stage = [&](int buf, int t0) {
#pragma unroll
    for (int it = 0; it < 2; ++it) {
      int c = it * 256 + tid, row = c >> 3, q = c & 7;
      int qs = (q ^ (row & 7)) << 3;
      GLOAD16(&Kall[(size_t)(t0 + row) * 1024 + h * 64 + qs], &Ks[buf][c * 8]);
      GLOAD16(&VtAll[(size_t)(h * 64 + row) * 2048 + t0 + qs], &Vs[buf][c * 8]);
    }
  };
  stage(0, tBeg);
  __syncthreads();
  int cur = 0;
  for (int t0 = tBeg; t0 < tEnd; t0 += 64) {
    if (t0 + 64 < tEnd) stage(cur ^ 1, t0 + 64);
    // S^T = K Q : sacc[sub][nf][rr] = S[t=nf*16+4g+rr][q=r]  (Q pre-scaled by log2e/8)
    f32x4 sacc[4][4] = {};
#pragma unroll
    for (int kk = 0; kk < 2; ++kk) {
      int qo = (((kk << 2) | g) ^ (r & 7)) << 3;
#pragma unroll
      for (int nf = 0; nf < 4; ++nf) {
        bf16x8 kf = ld_bf8(&Ks[cur][(nf * 16 + r) * 64 + qo]);
#pragma unroll
        for (int sub = 0; sub < 4; ++sub)
          sacc[sub][nf] = __builtin_amdgcn_mfma_f32_16x16x32_bf16(kf, qf[sub][kk], sacc[sub][nf], 0, 0, 0);
      }
    }
    // P = 2^sacc, pack to bf16 dwords c[sub][nf][s2] = {t=16nf+4g+2s2, +1}
    u32 c[4][4][2];
#pragma unroll
    for (int sub = 0; sub < 4; ++sub)
#pragma unroll
      for (int nf = 0; nf < 4; ++nf) {
        float p0 = __builtin_amdgcn_exp2f(sacc[sub][nf][0]);
        float p1 = __builtin_amdgcn_exp2f(sacc[sub][nf][1]);
        float p2 = __builtin_amdgcn_exp2f(sacc[sub][nf][2]);
        float p3 = __builtin_amdgcn_exp2f(sacc[sub][nf][3]);
        lsum[sub] += (p0 + p1) + (p2 + p3);
        c[sub][nf][0] = cvtpk(p0, p1);
        c[sub][nf][1] = cvtpk(p2, p3);
      }
    // O^T += V^T P^T : B-frag built in-register via permlane32+16 swap
#pragma unroll
    for (int kk = 0; kk < 2; ++kk) {
      int qo = (((kk << 2) | g) ^ (r & 7)) << 3;
      bf16x8 vf[4];
#pragma unroll
      for (int nf = 0; nf < 4; ++nf) vf[nf] = ld_bf8(&Vs[cur][(nf * 16 + r) * 64 + qo]);
#pragma unroll
      for (int sub = 0; sub < 4; ++sub) {
        u32 dw[4];
#pragma unroll
        for (int s2 = 0; s2 < 2; ++s2) {
          u32x2 t1 = __builtin_amdgcn_permlane32_swap(c[sub][2 * kk][s2], c[sub][2 * kk + 1][s2],
                                                      false, false);
          u32x2 t2 = __builtin_amdgcn_permlane16_swap(t1.x, t1.y, false, false);
          dw[s2] = t2.x; dw[2 + s2] = t2.y;
        }
        bf16x8 pB = __builtin_bit_cast(bf16x8, (u32x4){dw[0], dw[1], dw[2], dw[3]});
#pragma unroll
        for (int nf = 0; nf < 4; ++nf)
          o[sub][nf] = __builtin_amdgcn_mfma_f32_16x16x32_bf16(vf[nf], pB, o[sub][nf], 0, 0, 0);
      }
    }
    __syncthreads();
    cur ^= 1;
  }
  // epilogue: O^T layout — lane holds d = nf*16+4g+rr (consecutive rr), q = r
#pragma unroll
  for (int sub = 0; sub < 4; ++sub) {
    float ls = lsum[sub];
    ls += __shfl_xor(ls, 16, 64);
    ls += __shfl_xor(ls, 32, 64);
    int s = q0 + sub * 16 + r;
    if (l < 16) LP[(size_t)(ts * 16 + h) * 2048 + s] = ls;
#pragma unroll
    for (int nf = 0; nf < 4; ++nf) {
      uint2 pd;
      pd.x = cvtpk(o[sub][nf][0], o[sub][nf][1]);
      pd.y = cvtpk(o[sub][nf][2], o[sub][nf][3]);
      *(uint2*)&OP[((size_t)(ts * 16 + h) * 2048 + s) * 64 + nf * 16 + 4 * g] = pd;
    }
  }
}

// ---------------- out-proj partial GEMM with FUSED combine (no G buffer) ----------------
// block (bx, kz): A-tile = G[bx*128 .. +127][kz*64 .. +63] computed on the fly from OP/LP.
// G row m = bx*128+row -> h = bx, s = row*16 + kz, col c = kz*64 + d (d = 0..63).
__global__ __launch_bounds__(256) void oproj_part_kernel(const u16* __restrict__ OP,
                                                         const float* __restrict__ LP,
                                                         const u16* __restrict__ WoT,
                                                         float* __restrict__ Part) {
  __shared__ alignas(16) u16 As[128 * 64];
  __shared__ alignas(16) u16 Bs[64 * 64];
  int bx = blockIdx.x, kz = blockIdx.y, kt = kz * 64;
  int tid = threadIdx.x, w = tid >> 6, l = tid & 63, g = l >> 4, r = l & 15;
  // B stage (async) first so it overlaps the fused-combine math
#pragma unroll
  for (int it = 0; it < 2; ++it) {
    int c = it * 256 + tid, row = c >> 3, q = c & 7;
    GLOAD16(&WoT[(size_t)row * DIN + kt + ((q ^ (row & 7)) << 3)], &Bs[c * 8]);
  }
  // A stage: combine 4 T-split partials, normalize, write swizzled LDS
#pragma unroll
  for (int it = 0; it < 4; ++it) {
    int c = it * 256 + tid, row = c >> 3, q = c & 7, qs = q ^ (row & 7);
    int s = row * 16 + kz;
    float a8[8] = {};
    float lsum = 0.f;
#pragma unroll
    for (int ts = 0; ts < 4; ++ts) {
      u16x8 v = *(const u16x8*)&OP[((size_t)(ts * 16 + bx) * 2048 + s) * 64 + qs * 8];
#pragma unroll
      for (int e = 0; e < 8; ++e) a8[e] += bf2f(v[e]);
      lsum += LP[(size_t)(ts * 16 + bx) * 2048 + s];
    }
    float inv = 1.0f / lsum;
    u16x8 ov;
#pragma unroll
    for (int e = 0; e < 8; ++e) ov[e] = f2bf(a8[e] * inv);
    *(u16x8*)&As[c * 8] = ov;
  }
  __syncthreads();
  f32x4 acc[2][4] = {};
#pragma unroll
  for (int kk = 0; kk < 2; ++kk) {
    int qo = (((kk << 2) | g) ^ (r & 7)) << 3;
    bf16x8 a0 = ld_bf8(&As[(w * 32 + r) * 64 + qo]);
    bf16x8 a1 = ld_bf8(&As[(w * 32 + 16 + r) * 64 + qo]);
#pragma unroll
    for (int nf = 0; nf < 4; ++nf) {
      bf16x8 b = ld_bf8(&Bs[(nf * 16 + r) * 64 + qo]);
      acc[0][nf] = __builtin_amdgcn_mfma_f32_16x16x32_bf16(a0, b, acc[0][nf], 0, 0, 0);
      acc[1][nf] = __builtin_amdgcn_mfma_f32_16x16x32_bf16(a1, b, acc[1][nf], 0, 0, 0);
    }
  }
#pragma unroll
  for (int mi = 0; mi < 2; ++mi)
#pragma unroll
    for (int nf = 0; nf < 4; ++nf)
#pragma unroll
      for (int rr = 0; rr < 4; ++rr)
        Part[((size_t)kz * 2048 + bx * 128 + w * 32 + mi * 16 + 4 * g + rr) * 64 + nf * 16 + r] =
            acc[mi][nf][rr];
}

__global__ __launch_bounds__(256) void oproj_reduce_kernel(const float* __restrict__ Part,
                                                           const float* __restrict__ bo,
                                                           float* __restrict__ out) {
  int i4 = (blockIdx.x * 256 + threadIdx.x) * 4;  // 32768 threads x 4 f32
  int d = i4 & 63;
  float4 s = {bo[d], bo[d + 1], bo[d + 2], bo[d + 3]};
#pragma unroll
  for (int kz = 0; kz < 16; ++kz) {
    float4 p = *(const float4*)&Part[(size_t)kz * 131072 + i4];
    s.x += p.x; s.y += p.y; s.z += p.z; s.w += p.w;
  }
  *(float4*)&out[i4] = s;
}

extern "C" void kernel_launch(void* const* d_in, const int* in_sizes, int n_in,
                              void* d_out, int out_size, void* d_ws, size_t ws_size,
                              hipStream_t stream) {
  const float* cur = (const float*)d_in[0];
  const float* ctx = (const float*)d_in[1];
  const float* Wq = (const float*)d_in[2];
  const float* bq = (const float*)d_in[3];
  const float* Wk = (const float*)d_in[4];
  const float* bk = (const float*)d_in[5];
  const float* Wv = (const float*)d_in[6];
  const float* bv = (const float*)d_in[7];
  const float* Wo = (const float*)d_in[8];
  const float* bo = (const float*)d_in[9];
  float* out = (float*)d_out;

  char* ws = (char*)d_ws;
  const size_t MB = 1ull << 20;
  u16* cur_bf = (u16*)(ws + 0 * MB);
  u16* ctx_bf = (u16*)(ws + 4 * MB);
  u16* WqT    = (u16*)(ws + 8 * MB);
  u16* WkvT   = (u16*)(ws + 10 * MB);
  u16* WoT    = (u16*)(ws + 14 * MB);
  u16* Qall   = (u16*)(ws + 15 * MB);
  u16* Kall   = (u16*)(ws + 19 * MB);
  u16* VtAll  = (u16*)(ws + 23 * MB);
  u16* OP     = (u16*)(ws + 27 * MB);   // [4][16][2048][64] bf16 = 16MB
  float* LP   = (float*)(ws + 43 * MB); // [4][16][2048] f32 = 512KB
  float* Part = (float*)(ws + 44 * MB); // [16][2048][64] f32 = 8MB

  prep_kernel<<<2832, 256, 0, stream>>>(cur, ctx, Wq, Wk, Wv, Wo, cur_bf, ctx_bf,
                                        WqT, WkvT, WoT);
  gemm_qkv_kernel<<<768, 256, 0, stream>>>(cur_bf, ctx_bf, WqT, WkvT, bq, bk, bv,
                                           Qall, Kall, VtAll);
  attn_kernel<<<dim3(8, 16, 4), 256, 0, stream>>>(Qall, Kall, VtAll, OP, LP);
  oproj_part_kernel<<<dim3(16, 16), 256, 0, stream>>>(OP, LP, WoT, Part);
  oproj_reduce_kernel<<<128, 256, 0, stream>>>(Part, bo, out);
}